// Round 8
// baseline (246.266 us; speedup 1.0000x reference)
//
#include <hip/hip_runtime.h>
#include <math.h>

#define BIG_NEG -1.0e9f

typedef float f4 __attribute__((ext_vector_type(4)));

// Problem constants (fixed by setup_inputs)
constexpr int B  = 4;
constexpr int N1 = 511;
constexpr int C1 = 31;
constexpr int K  = 32;
constexpr int N  = N1 + 1;        // 512
constexpr int C  = C1 + 1;        // 32

// Workspace layout (float offsets)
constexpr int WS_TRANS = 0;                    // [32][32]
constexpr int WS_INIT  = 1024;                 // [32]
constexpr int WS_LEN   = 1056;                 // [32][32]  (K x C)
constexpr int WS_P     = 2080;                 // [64][64]  precision matrix
constexpr int WS_W2    = 6176;                 // [32][64]  w2[c][dd] row-major
constexpr int WS_BIAS  = 8224;                 // [32]

// ---------------------------------------------------------------------------
// Fused prep: rank-2 Gauss-Jordan (32 barriers) + small tables + w2 + bias.
// ---------------------------------------------------------------------------
__global__ __launch_bounds__(512) void k_prep(const float* __restrict__ tl,
                                              const float* __restrict__ il,
                                              const float* __restrict__ plr,
                                              const float* __restrict__ cov,
                                              const float* __restrict__ means,
                                              float* __restrict__ ws) {
    __shared__ float M[64][132];   // [cov | I], row stride 132 (16B aligned)
    __shared__ float cA[2][64];    // published pivot column s
    __shared__ float cB[2][64];    // published pivot column s+1
    __shared__ float piv[64];
    __shared__ float rpiv_s[64];
    __shared__ float mu[C1][64];
    __shared__ float s_logdet;

    const int tid = threadIdx.x;
    const int ii = tid >> 3;       // row 0..63
    const int cg = tid & 7;        // owns f4 chunks {cg, cg+8, cg+16, cg+24}

    f4* Mrow = (f4*)&M[ii][0];

    // ---- small tables (disjoint writers, no race) ----
    for (int idx = tid; idx < 1024; idx += 512) {
        const int i = idx >> 5, j = idx & 31;
        float lv;
        if (j < C1) {
            float lr = plr[j];
            lv = (float)i * lr - expf(lr) - lgammaf((float)i + 1.0f);
        } else {
            lv = (i == 1) ? 0.0f : BIG_NEG;
        }
        ws[WS_LEN + idx] = lv;
        if (i == C1) ws[WS_TRANS + idx] = 0.0f;
        else if (j == C1) ws[WS_TRANS + idx] = BIG_NEG;
    }
    // trans columns: log_softmax over axis 0 with masked diagonal
    if (tid < C1) {
        const int jj = tid;
        float m = BIG_NEG;
        for (int r = 0; r < C1; ++r) {
            float v = (r == jj) ? BIG_NEG : tl[r * C1 + jj];
            m = fmaxf(m, v);
        }
        float s = 0.0f;
        for (int r = 0; r < C1; ++r) {
            float v = (r == jj) ? BIG_NEG : tl[r * C1 + jj];
            s += expf(v - m);
        }
        float lse = m + logf(s);
        for (int r = 0; r < C1; ++r) {
            float v = (r == jj) ? BIG_NEG : tl[r * C1 + jj];
            ws[WS_TRANS + r * 32 + jj] = v - lse;
        }
    }
    // init_a
    if (tid == 32) {
        float m = -1.0e30f;
        for (int cc = 0; cc < C1; ++cc) m = fmaxf(m, il[cc]);
        float s = 0.0f;
        for (int cc = 0; cc < C1; ++cc) s += expf(il[cc] - m);
        float lse = m + logf(s);
        for (int cc = 0; cc < C1; ++cc) ws[WS_INIT + cc] = il[cc] - lse;
        ws[WS_INIT + C1] = BIG_NEG;
    }

    // ---- load [cov | I] ----
    {
        Mrow[cg]     = *(const f4*)&cov[ii * 64 + 4 * cg];
        Mrow[cg + 8] = *(const f4*)&cov[ii * 64 + 4 * (cg + 8)];
        const int r0 = 4 * cg, r1 = 4 * (cg + 8);
        f4 e1 = {(ii == r0) ? 1.f : 0.f, (ii == r0 + 1) ? 1.f : 0.f,
                 (ii == r0 + 2) ? 1.f : 0.f, (ii == r0 + 3) ? 1.f : 0.f};
        f4 e2 = {(ii == r1) ? 1.f : 0.f, (ii == r1 + 1) ? 1.f : 0.f,
                 (ii == r1 + 2) ? 1.f : 0.f, (ii == r1 + 3) ? 1.f : 0.f};
        Mrow[cg + 16] = e1;
        Mrow[cg + 24] = e2;
    }
    if (cg == 0) {
        cA[0][ii] = cov[ii * 64];      // column 0
        cB[0][ii] = cov[ii * 64 + 1];  // column 1
    }
    for (int idx = tid; idx < C1 * 64; idx += 512)
        mu[idx >> 6][idx & 63] = means[idx];
    __syncthreads();

    // ---- rank-2 Gauss-Jordan: 32 steps, ONE barrier each ----
    for (int s = 0; s < 64; s += 2) {
        const int par = (s >> 1) & 1;
        const float a1   = cA[par][ii];     // col s   of row ii
        const float b1   = cB[par][ii];     // col s+1 of row ii
        const float p1   = cA[par][s];
        const float cb_s = cB[par][s];      // row s, col s+1
        const float a1p  = cA[par][s + 1];  // row s+1, col s
        const float b1p  = cB[par][s + 1];  // row s+1, col s+1
        const float rp1 = __builtin_amdgcn_rcpf(p1);
        const float f1_i = a1 * rp1;
        const float f1_p = a1p * rp1;
        const float p2 = b1p - f1_p * cb_s;
        const float rp2 = __builtin_amdgcn_rcpf(p2);
        float aa, g1, g2;
        if (ii == s) {
            const float f2 = cb_s * rp2;
            aa = 1.0f + f2 * f1_p; g1 = 0.0f; g2 = f2;
        } else if (ii == s + 1) {
            aa = 1.0f; g1 = f1_p; g2 = 0.0f;
        } else {
            const float f2 = (b1 - f1_i * cb_s) * rp2;
            aa = 1.0f; g1 = f1_i - f2 * f1_p; g2 = f2;
        }
        if (tid == 0) { piv[s] = p1; piv[s + 1] = p2; }
        const f4* Ms  = (const f4*)&M[s][0];
        const f4* Ms1 = (const f4*)&M[s + 1][0];
        const int pubk0 = (s + 2) & ~3;     // chunk holding cols s+2, s+3
#pragma unroll
        for (int h = 0; h < 4; ++h) {
            const int q = cg + 8 * h;
            const int k0 = 4 * q;
            // active cols at this step: {s..63} U {64..64+s+1}
            const bool active = (k0 < 64) ? (k0 + 3 >= s) : (k0 - 64 <= s + 1);
            if (!active) continue;
            f4 v = aa * Mrow[q] - g1 * Ms[q] - g2 * Ms1[q];
            Mrow[q] = v;
            if (s < 62 && k0 == pubk0) {
                const int d = (s + 2) & 3;  // 0 or 2
                cA[par ^ 1][ii] = (d == 0) ? v.x : v.z;
                cB[par ^ 1][ii] = (d == 0) ? v.y : v.w;
            }
        }
        __syncthreads();
    }

    // ---- logdet (parallel, wave0) + reciprocal pivots ----
    if (tid < 64) {
        float lp = logf(piv[tid]);
        rpiv_s[tid] = 1.0f / piv[tid];
        for (int m2 = 32; m2 >= 1; m2 >>= 1) lp += __shfl_xor(lp, m2, 64);
        if (tid == 0) s_logdet = lp;
    }
    __syncthreads();

    // ---- P = inv(cov) to global: P[ii][c] = M[ii][64+c] * rpiv[ii] ----
    {
        const float rp = rpiv_s[ii];
        f4 a = Mrow[16 + cg] * rp;
        f4 b = Mrow[24 + cg] * rp;
        *(f4*)&ws[WS_P + ii * 64 + 4 * cg] = a;
        *(f4*)&ws[WS_P + ii * 64 + 32 + 4 * cg] = b;
    }

    // ---- w2[c][dd] = rpiv[dd] * (row_dd(Mright) . mu_c); bias via shfl ----
    {
        const int c = tid >> 4;    // 0..31
        const int l = tid & 15;
        if (c < C1) {
            const f4* muc = (const f4*)&mu[c][0];
            float qacc = 0.0f;
#pragma unroll
            for (int h = 0; h < 4; ++h) {
                const int dd = l + 16 * h;
                const f4* Mr = (const f4*)&M[dd][64];
                f4 a4 = {0.f, 0.f, 0.f, 0.f};
#pragma unroll
                for (int e4 = 0; e4 < 16; ++e4) a4 += Mr[e4] * muc[e4];
                float a = (a4.x + a4.y) + (a4.z + a4.w);
                a *= rpiv_s[dd];
                ws[WS_W2 + c * 64 + dd] = a;
                qacc += a * mu[c][dd];
            }
            for (int m2 = 8; m2 >= 1; m2 >>= 1) qacc += __shfl_xor(qacc, m2, 64);
            if (l == 0)
                ws[WS_BIAS + c] =
                    -0.5f * (64.0f * 1.8378770664093453f + s_logdet + qacc);
        }
    }
}

// ---------------------------------------------------------------------------
// Fused main: one block per (b,t). Stage feat rows t..t+31 in LDS, compute
// the 32 emission rows in-block (redundant across blocks, hidden under the
// store-BW bound), local prefix scan, then 32 coalesced f4 stores per thread.
// ---------------------------------------------------------------------------
__global__ __launch_bounds__(256) void k_main(const float* __restrict__ feat,
                                              const float* __restrict__ ws,
                                              float* __restrict__ out) {
    const int bid = blockIdx.x;
    const int b = bid / N1, t = bid % N1;
    const int tid = threadIdx.x;
    const int w = tid >> 6, lane = tid & 63;
    __shared__ float sx[32][64];   // feat rows t..t+31 (zeros when n >= N1)
    __shared__ float sh[32][36];   // emission rows -> inclusive scan

    // ---- stage x rows: 512 f4 loads, 2 per thread ----
#pragma unroll
    for (int rep = 0; rep < 2; ++rep) {
        const int fi = tid + 256 * rep;      // 0..511
        const int row = fi >> 4;
        const int c4 = (fi & 15) << 2;
        const int n = t + row;
        f4 v = {0.f, 0.f, 0.f, 0.f};
        if (n < N1) v = *(const f4*)&feat[(b * N1 + n) * 64 + c4];
        *(f4*)&sx[row][c4] = v;
    }
    __syncthreads();

    // ---- emission rows r = w, w+4, ..., w+28 per wave ----
    for (int r = w; r < 32; r += 4) {
        const int n = t + r;
        float val;
        if (n < N1) {
            const f4* xr = (const f4*)&sx[r][0];
            // z_lane = P[lane][:] . x  (P symmetric, row-major f4 reads)
            const f4* Pr = (const f4*)&ws[WS_P + lane * 64];
            f4 acc4 = {0.f, 0.f, 0.f, 0.f};
#pragma unroll
            for (int e = 0; e < 16; ++e) acc4 += Pr[e] * xr[e];
            float xz = sx[r][lane] * ((acc4.x + acc4.y) + (acc4.z + acc4.w));
            for (int m2 = 32; m2 >= 1; m2 >>= 1) xz += __shfl_xor(xz, m2);
            val = BIG_NEG;
            if (lane < C1) {
                const f4* Wr = (const f4*)&ws[WS_W2 + lane * 64];
                f4 wa = {0.f, 0.f, 0.f, 0.f};
#pragma unroll
                for (int e = 0; e < 16; ++e) wa += Wr[e] * xr[e];
                val = ws[WS_BIAS + lane] - 0.5f * xz +
                      ((wa.x + wa.y) + (wa.z + wa.w));
            }
        } else if (n == N1) {
            val = (lane == C1) ? 0.0f : BIG_NEG;   // EOS row
        } else {
            val = 0.0f;                             // zero padding
        }
        if (lane < 32) sh[r][lane] = val;
    }
    __syncthreads();

    // ---- parallel inclusive prefix scan along rows, per column ----
    {
        const int sc = tid >> 3;   // column 0..31
        const int g  = tid & 7;    // row group 0..7 (within-wave for shfl)
        float p0 = sh[4 * g + 0][sc];
        float p1 = p0 + sh[4 * g + 1][sc];
        float p2 = p1 + sh[4 * g + 2][sc];
        float p3 = p2 + sh[4 * g + 3][sc];
        float sum = p3;
#pragma unroll
        for (int off = 1; off < 8; off <<= 1) {
            float nv = __shfl_up(sum, off, 8);
            if (g >= off) sum += nv;
        }
        const float excl = sum - p3;
        sh[4 * g + 0][sc] = p0 + excl;
        sh[4 * g + 1][sc] = p1 + excl;
        sh[4 * g + 2][sc] = p2 + excl;
        sh[4 * g + 3][sc] = p3 + excl;
    }

    const int cp = tid >> 3;
    const int c0 = (tid & 7) << 2;
    f4 pre = *(const f4*)&ws[WS_TRANS + cp * 32 + c0];
    if (t == 0) {
        f4 in4 = *(const f4*)&ws[WS_INIT + c0];
        pre = pre + in4;
    }
    const float emisN = (cp == C1) ? 0.0f : BIG_NEG;
    const int keos = N1 - t;  // matches k only when 1 <= keos <= 31
    const size_t obase = (size_t)bid * (K * C * C) + (size_t)(cp * 32 + c0);
    __syncthreads();

#pragma unroll 4
    for (int k = 0; k < K; ++k) {
        f4 len4 = *(const f4*)&ws[WS_LEN + k * 32 + c0];
        f4 w4 = {0.f, 0.f, 0.f, 0.f};
        if (k > 0) w4 = *(const f4*)&sh[k - 1][c0];
        f4 o = pre + len4 + w4;
        if (k == keos) o = o + emisN;
        *(f4*)&out[obase + (size_t)k * (C * C)] = o;
    }
}

// ---------------------------------------------------------------------------
extern "C" void kernel_launch(void* const* d_in, const int* in_sizes, int n_in,
                              void* d_out, int out_size, void* d_ws, size_t ws_size,
                              hipStream_t stream) {
    const float* feat = (const float*)d_in[0];
    const float* tl   = (const float*)d_in[1];
    const float* il   = (const float*)d_in[2];
    const float* plr  = (const float*)d_in[3];
    const float* gm   = (const float*)d_in[4];
    const float* gc   = (const float*)d_in[5];
    float* ws  = (float*)d_ws;
    float* out = (float*)d_out;

    hipLaunchKernelGGL(k_prep, dim3(1), dim3(512), 0, stream, tl, il, plr, gc, gm, ws);
    hipLaunchKernelGGL(k_main, dim3(B * N1), dim3(256), 0, stream, feat, ws, out);
}

// Round 9
// 79.984 us; speedup vs baseline: 3.0789x; 3.0789x over previous
//
#include <hip/hip_runtime.h>
#include <math.h>

#define BIG_NEG -1.0e9f

typedef float f4 __attribute__((ext_vector_type(4)));

// Problem constants (fixed by setup_inputs)
constexpr int B  = 4;
constexpr int N1 = 511;
constexpr int C1 = 31;
constexpr int K  = 32;
constexpr int N  = N1 + 1;        // 512
constexpr int C  = C1 + 1;        // 32

// Workspace layout (float offsets)
constexpr int WS_TRANS = 0;                    // [32][32]
constexpr int WS_INIT  = 1024;                 // [32]
constexpr int WS_LEN   = 1056;                 // [32][32]  (K x C)
constexpr int WS_P     = 2080;                 // [64][64]  precision matrix
constexpr int WS_W     = 6176;                 // [64][32]  wT[dd][c]
constexpr int WS_BIAS  = 8224;                 // [32]
constexpr int WS_EMIS  = 8256;                 // [B][N][C] = 65536

// ---------------------------------------------------------------------------
// Fused prep: rank-4 frozen-pivot-row block Gauss-Jordan (16 barriers).
// Invariant: row ops are pure additions (det-preserving); pivot rows are
// never modified during their own step, so the final left half is
// blockdiag(B_k) and  P = blockdiag(B_k)^{-1} * Mright,  logdet = sum log det B_k.
// ---------------------------------------------------------------------------
__global__ __launch_bounds__(512) void k_prep(const float* __restrict__ tl,
                                              const float* __restrict__ il,
                                              const float* __restrict__ plr,
                                              const float* __restrict__ cov,
                                              const float* __restrict__ means,
                                              float* __restrict__ ws) {
    __shared__ float M[64][132];    // [cov | I], row stride 132 (16B aligned)
    __shared__ float cP[2][4][64];  // published pivot cols s..s+3 (dbuf)
    __shared__ float Bsave[16][16]; // B_k blocks, row-major
    __shared__ float mu[C1][64];

    const int tid = threadIdx.x;
    const int ii = tid >> 3;       // row 0..63
    const int cg = tid & 7;        // owns f4 chunks {cg, cg+8, cg+16, cg+24}

    f4* Mrow = (f4*)&M[ii][0];

    // ---- small tables (disjoint writers, no race) ----
    for (int idx = tid; idx < 1024; idx += 512) {
        const int i = idx >> 5, j = idx & 31;
        float lv;
        if (j < C1) {
            float lr = plr[j];
            lv = (float)i * lr - expf(lr) - lgammaf((float)i + 1.0f);
        } else {
            lv = (i == 1) ? 0.0f : BIG_NEG;
        }
        ws[WS_LEN + idx] = lv;
        if (i == C1) ws[WS_TRANS + idx] = 0.0f;
        else if (j == C1) ws[WS_TRANS + idx] = BIG_NEG;
    }
    if (tid < B * C) {
        const int bb = tid >> 5, cc = tid & 31;
        ws[WS_EMIS + (bb * N + N1) * C + cc] = (cc == C1) ? 0.0f : BIG_NEG;
    }
    // trans columns: log_softmax over axis 0 with masked diagonal
    if (tid < C1) {
        const int jj = tid;
        float m = BIG_NEG;
        for (int r = 0; r < C1; ++r) {
            float v = (r == jj) ? BIG_NEG : tl[r * C1 + jj];
            m = fmaxf(m, v);
        }
        float s = 0.0f;
        for (int r = 0; r < C1; ++r) {
            float v = (r == jj) ? BIG_NEG : tl[r * C1 + jj];
            s += expf(v - m);
        }
        float lse = m + logf(s);
        for (int r = 0; r < C1; ++r) {
            float v = (r == jj) ? BIG_NEG : tl[r * C1 + jj];
            ws[WS_TRANS + r * 32 + jj] = v - lse;
        }
    }
    // init_a
    if (tid == 32) {
        float m = -1.0e30f;
        for (int cc = 0; cc < C1; ++cc) m = fmaxf(m, il[cc]);
        float s = 0.0f;
        for (int cc = 0; cc < C1; ++cc) s += expf(il[cc] - m);
        float lse = m + logf(s);
        for (int cc = 0; cc < C1; ++cc) ws[WS_INIT + cc] = il[cc] - lse;
        ws[WS_INIT + C1] = BIG_NEG;
    }

    // ---- load [cov | I] ----
    {
        Mrow[cg]     = *(const f4*)&cov[ii * 64 + 4 * cg];
        Mrow[cg + 8] = *(const f4*)&cov[ii * 64 + 4 * (cg + 8)];
        const int r0 = 4 * cg, r1 = 4 * (cg + 8);
        f4 e1 = {(ii == r0) ? 1.f : 0.f, (ii == r0 + 1) ? 1.f : 0.f,
                 (ii == r0 + 2) ? 1.f : 0.f, (ii == r0 + 3) ? 1.f : 0.f};
        f4 e2 = {(ii == r1) ? 1.f : 0.f, (ii == r1 + 1) ? 1.f : 0.f,
                 (ii == r1 + 2) ? 1.f : 0.f, (ii == r1 + 3) ? 1.f : 0.f};
        Mrow[cg + 16] = e1;
        Mrow[cg + 24] = e2;
    }
    if (cg == 0) {
        cP[0][0][ii] = cov[ii * 64 + 0];
        cP[0][1][ii] = cov[ii * 64 + 1];
        cP[0][2][ii] = cov[ii * 64 + 2];
        cP[0][3][ii] = cov[ii * 64 + 3];
    }
    for (int idx = tid; idx < C1 * 64; idx += 512)
        mu[idx >> 6][idx & 63] = means[idx];
    __syncthreads();

    // ---- rank-4 block GJ: 16 steps, ONE barrier each, pivot rows frozen ----
    float detprod = 1.0f;
    for (int st = 0; st < 16; ++st) {
        const int s = st << 2;
        const int par = st & 1;
        // T = B^T : T[i][j] = cP[par][i][s+j]
        const float T00 = cP[par][0][s + 0], T01 = cP[par][0][s + 1],
                    T02 = cP[par][0][s + 2], T03 = cP[par][0][s + 3];
        const float T10 = cP[par][1][s + 0], T11 = cP[par][1][s + 1],
                    T12 = cP[par][1][s + 2], T13 = cP[par][1][s + 3];
        const float T20 = cP[par][2][s + 0], T21 = cP[par][2][s + 1],
                    T22 = cP[par][2][s + 2], T23 = cP[par][2][s + 3];
        const float T30 = cP[par][3][s + 0], T31 = cP[par][3][s + 1],
                    T32 = cP[par][3][s + 2], T33 = cP[par][3][s + 3];
        // LU of T (Doolittle, no pivoting; Schur blocks of SPD are SPD)
        const float r0 = __builtin_amdgcn_rcpf(T00);
        const float l10 = T10 * r0, l20 = T20 * r0, l30 = T30 * r0;
        const float u11 = T11 - l10 * T01, u12 = T12 - l10 * T02,
                    u13 = T13 - l10 * T03;
        const float r1 = __builtin_amdgcn_rcpf(u11);
        const float l21 = (T21 - l20 * T01) * r1;
        const float l31 = (T31 - l30 * T01) * r1;
        const float u22 = T22 - l20 * T02 - l21 * u12;
        const float u23 = T23 - l20 * T03 - l21 * u13;
        const float u32 = T32 - l30 * T02 - l31 * u12;
        const float u33t = T33 - l30 * T03 - l31 * u13;
        const float r2 = __builtin_amdgcn_rcpf(u22);
        const float l32 = u32 * r2;
        const float u33 = u33t - l32 * u23;
        const float r3 = __builtin_amdgcn_rcpf(u33);
        detprod *= T00 * u11 * u22 * u33;

        if (tid < 16) Bsave[st][tid] = cP[par][tid & 3][s + (tid >> 2)];

        // g solves g.B = m  (i.e. T g = m), m = row ii entries in cols s..s+3
        const float m0 = cP[par][0][ii], m1 = cP[par][1][ii],
                    m2 = cP[par][2][ii], m3 = cP[par][3][ii];
        const float y0 = m0;
        const float y1 = m1 - l10 * y0;
        const float y2 = m2 - l20 * y0 - l21 * y1;
        const float y3 = m3 - l30 * y0 - l31 * y1 - l32 * y2;
        float g3 = y3 * r3;
        float g2 = (y2 - u23 * g3) * r2;
        float g1 = (y1 - u12 * g2 - u13 * g3) * r1;
        float g0 = (y0 - T01 * g1 - T02 * g2 - T03 * g3) * r0;
        const bool pivrow = (unsigned)(ii - s) < 4u;
        if (pivrow) { g0 = 0.f; g1 = 0.f; g2 = 0.f; g3 = 0.f; }

        const f4* Ms0 = (const f4*)&M[s + 0][0];
        const f4* Ms1 = (const f4*)&M[s + 1][0];
        const f4* Ms2 = (const f4*)&M[s + 2][0];
        const f4* Ms3 = (const f4*)&M[s + 3][0];
        const int qpub = st + 1;   // chunk holding cols s+4..s+7
#pragma unroll
        for (int h = 0; h < 4; ++h) {
            const int q = cg + 8 * h;
            const int k0 = 4 * q;
            // active cols: {s..63} U {64..64+s+3}
            const bool active = (k0 < 64) ? (k0 + 3 >= s) : (k0 - 64 <= s + 3);
            if (!active) continue;
            f4 v = Mrow[q] - g0 * Ms0[q] - g1 * Ms1[q]
                           - g2 * Ms2[q] - g3 * Ms3[q];
            if (!pivrow) Mrow[q] = v;      // pivot rows frozen (no race)
            if (st < 15 && q == qpub) {
                cP[par ^ 1][0][ii] = v.x;
                cP[par ^ 1][1][ii] = v.y;
                cP[par ^ 1][2][ii] = v.z;
                cP[par ^ 1][3][ii] = v.w;
            }
        }
        __syncthreads();
    }

    // ---- extraction: P[ii][:] = (invB_k row (ii&3)) . Mright[4k..4k+3][:] ----
    {
        const int kb = ii >> 2, rsel = ii & 3, base = kb << 2;
        // T' = B_k^T : T'[i][j] = Bsave[kb][j*4+i]
        const float* Bk = &Bsave[kb][0];
        const float T00 = Bk[0],  T01 = Bk[4],  T02 = Bk[8],  T03 = Bk[12];
        const float T10 = Bk[1],  T11 = Bk[5],  T12 = Bk[9],  T13 = Bk[13];
        const float T20 = Bk[2],  T21 = Bk[6],  T22 = Bk[10], T23 = Bk[14];
        const float T30 = Bk[3],  T31 = Bk[7],  T32 = Bk[11], T33 = Bk[15];
        const float r0 = __builtin_amdgcn_rcpf(T00);
        const float l10 = T10 * r0, l20 = T20 * r0, l30 = T30 * r0;
        const float u11 = T11 - l10 * T01, u12 = T12 - l10 * T02,
                    u13 = T13 - l10 * T03;
        const float r1 = __builtin_amdgcn_rcpf(u11);
        const float l21 = (T21 - l20 * T01) * r1;
        const float l31 = (T31 - l30 * T01) * r1;
        const float u22 = T22 - l20 * T02 - l21 * u12;
        const float u23 = T23 - l20 * T03 - l21 * u13;
        const float u32 = T32 - l30 * T02 - l31 * u12;
        const float u33t = T33 - l30 * T03 - l31 * u13;
        const float r2 = __builtin_amdgcn_rcpf(u22);
        const float l32 = u32 * r2;
        const float u33 = u33t - l32 * u23;
        const float r3 = __builtin_amdgcn_rcpf(u33);
        // solve T' x = e_rsel
        const float m0 = (rsel == 0) ? 1.f : 0.f;
        const float m1 = (rsel == 1) ? 1.f : 0.f;
        const float m2 = (rsel == 2) ? 1.f : 0.f;
        const float m3 = (rsel == 3) ? 1.f : 0.f;
        const float y0 = m0;
        const float y1 = m1 - l10 * y0;
        const float y2 = m2 - l20 * y0 - l21 * y1;
        const float y3 = m3 - l30 * y0 - l31 * y1 - l32 * y2;
        const float x3 = y3 * r3;
        const float x2 = (y2 - u23 * x3) * r2;
        const float x1 = (y1 - u12 * x2 - u13 * x3) * r1;
        const float x0 = (y0 - T01 * x1 - T02 * x2 - T03 * x3) * r0;

        const f4* R0 = (const f4*)&M[base + 0][64];
        const f4* R1 = (const f4*)&M[base + 1][64];
        const f4* R2 = (const f4*)&M[base + 2][64];
        const f4* R3 = (const f4*)&M[base + 3][64];
        f4 va = x0 * R0[cg] + x1 * R1[cg] + x2 * R2[cg] + x3 * R3[cg];
        f4 vb = x0 * R0[cg + 8] + x1 * R1[cg + 8] +
                x2 * R2[cg + 8] + x3 * R3[cg + 8];
        *(f4*)&ws[WS_P + ii * 64 + 4 * cg] = va;
        *(f4*)&ws[WS_P + ii * 64 + 32 + 4 * cg] = vb;
        *(f4*)&M[ii][4 * cg] = va;          // stash P in left half for w2
        *(f4*)&M[ii][32 + 4 * cg] = vb;
    }
    __syncthreads();

    // ---- wT[dd][c] = P[dd][:] . mu_c ; bias via shfl ----
    {
        const int c = tid >> 4;    // 0..31
        const int l = tid & 15;
        if (c < C1) {
            const f4* muc = (const f4*)&mu[c][0];
            float qacc = 0.0f;
#pragma unroll
            for (int h = 0; h < 4; ++h) {
                const int dd = l + 16 * h;
                const f4* Mr = (const f4*)&M[dd][0];
                f4 a4 = {0.f, 0.f, 0.f, 0.f};
#pragma unroll
                for (int e4 = 0; e4 < 16; ++e4) a4 += Mr[e4] * muc[e4];
                float a = (a4.x + a4.y) + (a4.z + a4.w);
                ws[WS_W + dd * 32 + c] = a;
                qacc += a * mu[c][dd];
            }
            for (int m2 = 8; m2 >= 1; m2 >>= 1) qacc += __shfl_xor(qacc, m2, 64);
            if (l == 0)
                ws[WS_BIAS + c] = -0.5f * (64.0f * 1.8378770664093453f +
                                           logf(detprod) + qacc);
        }
    }
}

// ---------------------------------------------------------------------------
// Emission log-probs: emis[b,n,c] = bias_c + w_c.x - 0.5 * x^T P x
// 4 waves per block, one wave per (b,n); coalesced P reads (lane-contiguous).
// ---------------------------------------------------------------------------
__global__ __launch_bounds__(256) void k_emis(const float* __restrict__ feat,
                                              float* __restrict__ ws) {
    const int tid = threadIdx.x;
    const int w = tid >> 6, lane = tid & 63;
    const int flat = blockIdx.x * 4 + w;          // == b*N1 + n, 0..2043
    const int b = flat / N1, n = flat % N1;
    __shared__ float xs[4][64];

    const float x = feat[flat * 64 + lane];
    xs[w][lane] = x;   // wave-local slice; lgkmcnt ordering suffices

    const float* __restrict__ P = ws + WS_P;
    float z = 0.0f;
    for (int dd = 0; dd < 64; ++dd) z += P[dd * 64 + lane] * xs[w][dd];

    float xz = x * z;
    for (int m = 32; m >= 1; m >>= 1) xz += __shfl_xor(xz, m);

    float val = BIG_NEG;
    if (lane < C1) {
        float s = ws[WS_BIAS + lane] - 0.5f * xz;
        const float* __restrict__ wT = ws + WS_W;
        for (int dd = 0; dd < 64; ++dd) s += wT[dd * 32 + lane] * xs[w][dd];
        val = s;
    }
    if (lane < C) ws[WS_EMIS + (b * N + n) * C + lane] = val;
}

// ---------------------------------------------------------------------------
// Main assembly (local window-scan): one block per (b,t); loads emis rows
// t..t+31 into LDS, parallel per-column prefix scan (depth 4+3), then 32
// coalesced plain f4 stores per thread along k.
// ---------------------------------------------------------------------------
__global__ __launch_bounds__(256) void k_main(const float* __restrict__ ws,
                                              float* __restrict__ out) {
    const int bid = blockIdx.x;
    const int b = bid / N1, t = bid % N1;
    const int tid = threadIdx.x;
    __shared__ float sh[32][36];   // stride 36: 16B-aligned rows, spread banks

    // load emis rows t..t+31 (zero past row N-1)
    {
        const int row = tid >> 3;            // 0..31
        const int c4 = (tid & 7) << 2;       // 0,4,...,28
        f4 v = {0.f, 0.f, 0.f, 0.f};
        if (t + row < N)
            v = *(const f4*)&ws[WS_EMIS + (b * N + t + row) * C + c4];
        *(f4*)&sh[row][c4] = v;
    }
    __syncthreads();

    // parallel inclusive prefix scan along rows, per column:
    // 8 threads per column, 4 serial rows each, then shfl_up scan over groups.
    {
        const int sc = tid >> 3;   // column 0..31
        const int g  = tid & 7;    // row group 0..7 (within-wave for shfl)
        float p0 = sh[4 * g + 0][sc];
        float p1 = p0 + sh[4 * g + 1][sc];
        float p2 = p1 + sh[4 * g + 2][sc];
        float p3 = p2 + sh[4 * g + 3][sc];
        float sum = p3;
#pragma unroll
        for (int off = 1; off < 8; off <<= 1) {
            float nv = __shfl_up(sum, off, 8);
            if (g >= off) sum += nv;
        }
        const float excl = sum - p3;
        sh[4 * g + 0][sc] = p0 + excl;
        sh[4 * g + 1][sc] = p1 + excl;
        sh[4 * g + 2][sc] = p2 + excl;
        sh[4 * g + 3][sc] = p3 + excl;
    }

    const int cp = tid >> 3;
    const int c0 = (tid & 7) << 2;
    f4 pre = *(const f4*)&ws[WS_TRANS + cp * 32 + c0];
    if (t == 0) {
        f4 in4 = *(const f4*)&ws[WS_INIT + c0];
        pre = pre + in4;
    }
    const float emisN = (cp == C1) ? 0.0f : BIG_NEG;
    const int keos = N1 - t;  // matches k only when 1 <= keos <= 31
    const size_t obase = (size_t)bid * (K * C * C) + (size_t)(cp * 32 + c0);
    __syncthreads();

#pragma unroll 4
    for (int k = 0; k < K; ++k) {
        f4 len4 = *(const f4*)&ws[WS_LEN + k * 32 + c0];
        f4 w4 = {0.f, 0.f, 0.f, 0.f};
        if (k > 0) w4 = *(const f4*)&sh[k - 1][c0];
        f4 o = pre + len4 + w4;
        if (k == keos) o = o + emisN;
        *(f4*)&out[obase + (size_t)k * (C * C)] = o;
    }
}

// ---------------------------------------------------------------------------
extern "C" void kernel_launch(void* const* d_in, const int* in_sizes, int n_in,
                              void* d_out, int out_size, void* d_ws, size_t ws_size,
                              hipStream_t stream) {
    const float* feat = (const float*)d_in[0];
    const float* tl   = (const float*)d_in[1];
    const float* il   = (const float*)d_in[2];
    const float* plr  = (const float*)d_in[3];
    const float* gm   = (const float*)d_in[4];
    const float* gc   = (const float*)d_in[5];
    float* ws  = (float*)d_ws;
    float* out = (float*)d_out;

    hipLaunchKernelGGL(k_prep, dim3(1), dim3(512), 0, stream, tl, il, plr, gc, gm, ws);
    hipLaunchKernelGGL(k_emis, dim3(B * N1 / 4), dim3(256), 0, stream, feat, ws);
    hipLaunchKernelGGL(k_main, dim3(B * N1), dim3(256), 0, stream, ws, out);
}